// Round 3
// baseline (146.703 us; speedup 1.0000x reference)
//
#include <hip/hip_runtime.h>

#define T_STEPS 128
#define DIM 1024
#define ODE_UNFOLDS 6
#define EPS 1e-8f
#define L2E 1.44269504088896340736f

__device__ __forceinline__ float fexp2(float x) { return __builtin_amdgcn_exp2f(x); }
__device__ __forceinline__ float frcp(float x)  { return __builtin_amdgcn_rcpf(x); }

__device__ __forceinline__ float softplus_init(float x) {
  // init-only (once per thread); x in (0,1] here so no overflow concerns
  return log2f(1.0f + exp2f(x * L2E)) * (1.0f / L2E);
}

// swap adjacent lane pairs (0<->1, 2<->3, ...): v_mov_b32_dpp quad_perm:[1,0,3,2]
// full-rate VALU, no LDS/lgkm latency on the recurrence critical path
__device__ __forceinline__ float swap_adj(float x) {
  int y = __builtin_amdgcn_mov_dpp(__float_as_int(x), 0xB1, 0xF, 0xF, true);
  return __int_as_float(y);
}

// 512-thread blocks: 8 waves / 4 SIMDs = 2 waves per SIMD. At 1 wave/SIMD the
// recurrence is trans-latency-bound (~35% stall); a second resident wave fills
// those issue slots. 128 blocks -> 1 block/CU on 128 CUs (other CUs idle; the
// chain count B*U is fixed, concentrating beats spreading-thin here).
__global__ __launch_bounds__(512) void memcell_kernel(
    const float* __restrict__ inputs,      // (B,T,DIM)
    const float* __restrict__ gleak,       // (U)
    const float* __restrict__ vleak,       // (U)
    const float* __restrict__ cm,          // (U)
    const float* __restrict__ w,           // (U,2)
    const float* __restrict__ sigma,       // (U,2)
    const float* __restrict__ mu,          // (U,2)
    const float* __restrict__ erev,        // (U,2)
    const float* __restrict__ sens_w,      // (U)
    const float* __restrict__ sens_sigma,  // (U)
    const float* __restrict__ sens_mu,     // (U)
    const float* __restrict__ sens_erev,   // (U)
    const float* __restrict__ input_w,     // (DIM)
    const float* __restrict__ input_b,     // (DIM)
    const float* __restrict__ output_w,    // (DIM)
    const float* __restrict__ output_b,    // (DIM)
    float* __restrict__ out)               // (B,DIM)
{
  const int tid  = blockIdx.x * blockDim.x + threadIdx.x;  // [0, B*U)
  const int p    = tid >> 1;          // chain index: b*DIM + col
  const int half = tid & 1;           // 0: unit=col, 1: unit=col+DIM
  const int b    = p >> 10;           // DIM == 1024
  const int col  = p & (DIM - 1);
  const int u    = col + (half << 10);

  // ---- per-thread constants (loaded/derived once) ----
  const float spw0  = softplus_init(w[2*u]);
  const float spw1  = softplus_init(w[2*u+1]);
  const float e0    = erev[2*u];
  const float e1    = erev[2*u+1];
  const float spw0e = spw0 * e0;
  const float spw1e = spw1 * e1;
  const float sg0   = sigma[2*u],  sg1 = sigma[2*u+1];
  const float mu0   = mu[2*u],     mu1 = mu[2*u+1];
  // sigmoid((v-mu)*sg) = 1/(1 + exp2(fma(v, -sg*L2E, mu*sg*L2E)))
  const float negA0 = -sg0 * L2E,  B0c = mu0 * sg0 * L2E;
  const float negA1 = -sg1 * L2E,  B1c = mu1 * sg1 * L2E;
  const float gl    = softplus_init(gleak[u]);
  const float glv   = gl * vleak[u];
  const float cmt   = softplus_init(cm[u]) * (float)ODE_UNFOLDS;
  const float dbase = cmt + gl + EPS;
  const float spsw  = softplus_init(sens_w[u]);
  const float ssg   = sens_sigma[u];
  const float smu   = sens_mu[u];
  const float negAs = -ssg * L2E,  Bsc = smu * ssg * L2E;
  const float serev = sens_erev[u];
  const float iw    = input_w[col];
  const float ib    = input_b[col];

  // partner's synapse-1 exp-arg constants: each lane computes the partner's t1
  // locally from its OWN v (same-cost fma), result swapped AFTER exp2 so the
  // DPP overlaps the own-path a0/p computation instead of heading the chain.
  const float negA1p = swap_adj(negA1);
  const float B1p    = swap_adj(B1c);

  const float* xp = inputs + ((size_t)b * T_STEPS) * DIM + col;

  // 4-deep x prefetch pipeline (hides HBM latency)
  float xs0 = xp[0 * DIM];
  float xs1 = xp[1 * DIM];
  float xs2 = xp[2 * DIM];
  float xs3 = xp[3 * DIM];

  float v = 0.0f;

  for (int tb = 0; tb < T_STEPS; tb += 4) {
    const float c0 = xs0, c1 = xs1, c2 = xs2, c3 = xs3;
    if (tb + 4 < T_STEPS) {
      const float* nx = xp + (size_t)(tb + 4) * DIM;
      xs0 = nx[0 * DIM];
      xs1 = nx[1 * DIM];
      xs2 = nx[2 * DIM];
      xs3 = nx[3 * DIM];
    }
    #pragma unroll
    for (int j = 0; j < 4; ++j) {
      const float xr = (j == 0) ? c0 : (j == 1) ? c1 : (j == 2) ? c2 : c3;
      const float x  = fmaf(xr, iw, ib);
      // sensory synapse (once per step)
      const float ts    = fexp2(fmaf(x, negAs, Bsc));
      const float s     = spsw * frcp(1.0f + ts);
      const float ns    = fmaf(s, serev, glv);   // glv + num_s
      const float ds    = dbase + s;             // cmt + gl + eps + den_s
      const float dspw0 = ds + spw0;             // for the folded p-fma
      #pragma unroll
      for (int k = 0; k < ODE_UNFOLDS; ++k) {
        // multiply num & den through by a0*a1 -> one rcp per unfold.
        //   nume = a1*(numerN*a0 + spw0e) + spw1e*a0
        //   deno = a1*(ds*a0 + spw0)     + spw1 *a0
        // with the deno "+1" folded: ds*a0 + spw0 = fma(ds, t0, ds+spw0)
        const float z0  = fmaf(v, negA0,  B0c);
        const float z1p = fmaf(v, negA1p, B1p);   // partner's t1 arg, from MY v
        const float t0  = fexp2(z0);
        const float tp  = fexp2(z1p);
        const float t1  = swap_adj(tp);           // DPP off own path
        const float a0  = 1.0f + t0;
        const float numerN = fmaf(cmt, v, ns);    // off-chain
        const float q   = fmaf(numerN, a0, spw0e);
        const float e_t = spw1e * a0;
        const float p   = fmaf(ds, t0, dspw0);    // chain: t0 -> p (a0-add skipped)
        const float s_t = spw1 * a0;
        const float a1  = 1.0f + t1;
        const float nume = fmaf(a1, q, e_t);
        const float deno = fmaf(a1, p, s_t);
        const float r   = frcp(deno);
        v = nume * r;
      }
    }
  }

  if (half == 0) {
    out[(size_t)b * DIM + col] = fmaf(v, output_w[col], output_b[col]);
  }
}

extern "C" void kernel_launch(void* const* d_in, const int* in_sizes, int n_in,
                              void* d_out, int out_size, void* d_ws, size_t ws_size,
                              hipStream_t stream) {
  const float* inputs      = (const float*)d_in[0];
  const float* gleak       = (const float*)d_in[1];
  const float* vleak       = (const float*)d_in[2];
  const float* cm          = (const float*)d_in[3];
  const float* w           = (const float*)d_in[4];
  const float* sigma       = (const float*)d_in[5];
  const float* mu          = (const float*)d_in[6];
  const float* erev        = (const float*)d_in[7];
  const float* sens_w      = (const float*)d_in[8];
  const float* sens_sigma  = (const float*)d_in[9];
  const float* sens_mu     = (const float*)d_in[10];
  const float* sens_erev   = (const float*)d_in[11];
  const float* input_w     = (const float*)d_in[12];
  const float* input_b     = (const float*)d_in[13];
  const float* output_w    = (const float*)d_in[14];
  const float* output_b    = (const float*)d_in[15];

  const int B = in_sizes[0] / (T_STEPS * DIM);   // 32
  const int U = 2 * DIM;
  const int total_threads = B * U;               // 65536
  // 512-thread blocks -> 2 waves/SIMD (see kernel comment). 128 blocks.
  dim3 block(512);
  dim3 grid(total_threads / 512);                // 128 blocks
  memcell_kernel<<<grid, block, 0, stream>>>(
      inputs, gleak, vleak, cm, w, sigma, mu, erev,
      sens_w, sens_sigma, sens_mu, sens_erev,
      input_w, input_b, output_w, output_b, (float*)d_out);
}

// Round 4
// 142.345 us; speedup vs baseline: 1.0306x; 1.0306x over previous
//
#include <hip/hip_runtime.h>

#define T_STEPS 128
#define DIM 1024
#define ODE_UNFOLDS 6
#define EPS 1e-8f
#define L2E 1.44269504088896340736f

__device__ __forceinline__ float fexp2(float x) { return __builtin_amdgcn_exp2f(x); }
__device__ __forceinline__ float frcp(float x)  { return __builtin_amdgcn_rcpf(x); }

__device__ __forceinline__ float softplus_init(float x) {
  // init-only (once per thread); x in (0,1] here so no overflow concerns
  return log2f(1.0f + exp2f(x * L2E)) * (1.0f / L2E);
}

// quad_perm:[1,0,3,2] — swap adjacent lanes (0<->1, 2<->3). Full-rate VALU.
__device__ __forceinline__ float swap_adj(float x) {
  int y = __builtin_amdgcn_mov_dpp(__float_as_int(x), 0xB1, 0xF, 0xF, true);
  return __int_as_float(y);
}

// quad_perm:[0,2,2,0] (imm 0x28) — lanes 0,2 keep their value; lane1 <- lane2,
// lane3 <- lane0. Broadcasts the two canonical v-updates to the consumer lanes.
__device__ __forceinline__ float bcast02(float x) {
  int y = __builtin_amdgcn_mov_dpp(__float_as_int(x), 0x28, 0xF, 0xF, true);
  return __int_as_float(y);
}

// 4 lanes per (b,col) pair — one lane per (unit, synapse):
//   sub0: unit u0=col,     syn0, exp2 source v0
//   sub1: unit u0,         syn1, exp2 source v1
//   sub2: unit u1=col+DIM, syn0, exp2 source v1
//   sub3: unit u1,         syn1, exp2 source v0
// Each lane does ONE exp2/unfold (was two). DPP1 pairs the t's per unit;
// lanes 0,2 produce canonical v0/v1 updates; DPP2 [0,2,2,0] redistributes.
// 131072 threads -> 512 blocks -> 2 blocks/CU -> 2 waves/SIMD on all CUs,
// doubling TLP to hide the exp2/rcp dependency-latency stalls.
__global__ __launch_bounds__(256) void memcell_kernel(
    const float* __restrict__ inputs,      // (B,T,DIM)
    const float* __restrict__ gleak,       // (U)
    const float* __restrict__ vleak,       // (U)
    const float* __restrict__ cm,          // (U)
    const float* __restrict__ w,           // (U,2)
    const float* __restrict__ sigma,       // (U,2)
    const float* __restrict__ mu,          // (U,2)
    const float* __restrict__ erev,        // (U,2)
    const float* __restrict__ sens_w,      // (U)
    const float* __restrict__ sens_sigma,  // (U)
    const float* __restrict__ sens_mu,     // (U)
    const float* __restrict__ sens_erev,   // (U)
    const float* __restrict__ input_w,     // (DIM)
    const float* __restrict__ input_b,     // (DIM)
    const float* __restrict__ output_w,    // (DIM)
    const float* __restrict__ output_b,    // (DIM)
    float* __restrict__ out)               // (B,DIM)
{
  const int tid  = blockIdx.x * blockDim.x + threadIdx.x;  // [0, 2*B*U)
  const int sub  = tid & 3;           // role within the quad
  const int pp   = tid >> 2;          // pair index: b*DIM + col
  const int b    = pp >> 10;          // DIM == 1024
  const int col  = pp & (DIM - 1);
  const int half = sub >> 1;          // 0: unit=col, 1: unit=col+DIM
  const int syn  = sub & 1;           // which synapse this lane's exp2 serves
  const int u    = col + (half << 10);

  // ---- per-thread constants ----
  // update weights, keyed by Own = synapse of the lane's own t, Rec = other.
  const float wOwn  = softplus_init(w[2*u + syn]);
  const float wRec  = softplus_init(w[2*u + (1 - syn)]);
  const float wOwnE = wOwn * erev[2*u + syn];
  const float wRecE = wRec * erev[2*u + (1 - syn)];
  // own-synapse sigmoid constants: sigmoid((v-mu)*sg) = 1/(1+exp2(fma(v,-sg*L2E, mu*sg*L2E)))
  const float sg    = sigma[2*u + syn];
  const float muc   = mu[2*u + syn];
  const float negA  = -sg * L2E, Bc = muc * sg * L2E;
  const float gl    = softplus_init(gleak[u]);
  const float glv   = gl * vleak[u];
  const float cmt   = softplus_init(cm[u]) * (float)ODE_UNFOLDS;
  const float dbase = cmt + gl + EPS;
  const float spsw  = softplus_init(sens_w[u]);
  const float ssg   = sens_sigma[u];
  const float smu   = sens_mu[u];
  const float negAs = -ssg * L2E, Bsc = smu * ssg * L2E;
  const float serev = sens_erev[u];
  const float iw    = input_w[col];
  const float ib    = input_b[col];

  const float* xp = inputs + ((size_t)b * T_STEPS) * DIM + col;

  // 4-deep x prefetch pipeline
  float xs0 = xp[0 * DIM];
  float xs1 = xp[1 * DIM];
  float xs2 = xp[2 * DIM];
  float xs3 = xp[3 * DIM];

  float v_src  = 0.0f;   // feeds this lane's exp2
  float v_unit = 0.0f;   // this lane's unit state (canonical on lanes 0,2)

  for (int tb = 0; tb < T_STEPS; tb += 4) {
    const float c0 = xs0, c1 = xs1, c2 = xs2, c3 = xs3;
    if (tb + 4 < T_STEPS) {
      const float* nx = xp + (size_t)(tb + 4) * DIM;
      xs0 = nx[0 * DIM];
      xs1 = nx[1 * DIM];
      xs2 = nx[2 * DIM];
      xs3 = nx[3 * DIM];
    }
    #pragma unroll
    for (int j = 0; j < 4; ++j) {
      const float xr = (j == 0) ? c0 : (j == 1) ? c1 : (j == 2) ? c2 : c3;
      const float x  = fmaf(xr, iw, ib);
      // sensory synapse (once per step, per unit)
      const float ts    = fexp2(fmaf(x, negAs, Bsc));
      const float s     = spsw * frcp(1.0f + ts);
      const float ns    = fmaf(s, serev, glv);   // glv + num_s
      const float ds    = dbase + s;             // cmt + gl + eps + den_s
      const float dsOwn = ds + wOwn;             // for the folded p-fma
      #pragma unroll
      for (int k = 0; k < ODE_UNFOLDS; ++k) {
        // nume = aRec*(numerN*aOwn + wOwnE) + wRecE*aOwn
        // deno = aRec*(ds*aOwn + wOwn)     + wRec *aOwn   ("+1" folded into dsOwn)
        const float z     = fmaf(v_src, negA, Bc);
        const float t_own = fexp2(z);
        const float t_rec = swap_adj(t_own);      // partner synapse's t
        const float aOwn  = 1.0f + t_own;
        const float numerN = fmaf(cmt, v_unit, ns);
        const float q     = fmaf(numerN, aOwn, wOwnE);
        const float e_    = wRecE * aOwn;
        const float p     = fmaf(ds, t_own, dsOwn);
        const float s_    = wRec * aOwn;
        const float aRec  = 1.0f + t_rec;
        const float nume  = fmaf(aRec, q, e_);
        const float deno  = fmaf(aRec, p, s_);
        const float vN    = nume * frcp(deno);
        v_unit = vN;               // canonical on lanes 0,2; discarded path on 1,3
        v_src  = bcast02(vN);      // lane1 <- v1_new (lane2), lane3 <- v0_new (lane0)
      }
    }
  }

  if (sub == 0) {
    out[(size_t)b * DIM + col] = fmaf(v_unit, output_w[col], output_b[col]);
  }
}

extern "C" void kernel_launch(void* const* d_in, const int* in_sizes, int n_in,
                              void* d_out, int out_size, void* d_ws, size_t ws_size,
                              hipStream_t stream) {
  const float* inputs      = (const float*)d_in[0];
  const float* gleak       = (const float*)d_in[1];
  const float* vleak       = (const float*)d_in[2];
  const float* cm          = (const float*)d_in[3];
  const float* w           = (const float*)d_in[4];
  const float* sigma       = (const float*)d_in[5];
  const float* mu          = (const float*)d_in[6];
  const float* erev        = (const float*)d_in[7];
  const float* sens_w      = (const float*)d_in[8];
  const float* sens_sigma  = (const float*)d_in[9];
  const float* sens_mu     = (const float*)d_in[10];
  const float* sens_erev   = (const float*)d_in[11];
  const float* input_w     = (const float*)d_in[12];
  const float* input_b     = (const float*)d_in[13];
  const float* output_w    = (const float*)d_in[14];
  const float* output_b    = (const float*)d_in[15];

  const int B = in_sizes[0] / (T_STEPS * DIM);   // 32
  const int U = 2 * DIM;
  const int total_threads = 2 * B * U;           // 131072 (4 lanes per pair)
  dim3 block(256);
  dim3 grid(total_threads / 256);                // 512 blocks -> 2 waves/SIMD everywhere

  memcell_kernel<<<grid, block, 0, stream>>>(
      inputs, gleak, vleak, cm, w, sigma, mu, erev,
      sens_w, sens_sigma, sens_mu, sens_erev,
      input_w, input_b, output_w, output_b, (float*)d_out);
}

// Round 5
// 132.138 us; speedup vs baseline: 1.1102x; 1.0772x over previous
//
#include <hip/hip_runtime.h>

#define T_STEPS 128
#define DIM 1024
#define ODE_UNFOLDS 6
#define EPS 1e-8f
#define L2E 1.44269504088896340736f

__device__ __forceinline__ float fexp2(float x) { return __builtin_amdgcn_exp2f(x); }
__device__ __forceinline__ float frcp(float x)  { return __builtin_amdgcn_rcpf(x); }

__device__ __forceinline__ float softplus_init(float x) {
  // init-only (once per thread); x in (0,1] here so no overflow concerns
  return log2f(1.0f + exp2f(x * L2E)) * (1.0f / L2E);
}

// swap adjacent lane pairs (0<->1, 2<->3, ...): v_mov_b32_dpp quad_perm:[1,0,3,2]
// full-rate VALU; kept OFF the recurrence critical path (swap after exp2).
__device__ __forceinline__ float swap_adj(float x) {
  int y = __builtin_amdgcn_mov_dpp(__float_as_int(x), 0xB1, 0xF, 0xF, true);
  return __int_as_float(y);
}

__global__ __launch_bounds__(256) void memcell_kernel(
    const float* __restrict__ inputs,      // (B,T,DIM)
    const float* __restrict__ gleak,       // (U)
    const float* __restrict__ vleak,       // (U)
    const float* __restrict__ cm,          // (U)
    const float* __restrict__ w,           // (U,2)
    const float* __restrict__ sigma,       // (U,2)
    const float* __restrict__ mu,          // (U,2)
    const float* __restrict__ erev,        // (U,2)
    const float* __restrict__ sens_w,      // (U)
    const float* __restrict__ sens_sigma,  // (U)
    const float* __restrict__ sens_mu,     // (U)
    const float* __restrict__ sens_erev,   // (U)
    const float* __restrict__ input_w,     // (DIM)
    const float* __restrict__ input_b,     // (DIM)
    const float* __restrict__ output_w,    // (DIM)
    const float* __restrict__ output_b,    // (DIM)
    float* __restrict__ out)               // (B,DIM)
{
  const int tid  = blockIdx.x * blockDim.x + threadIdx.x;  // [0, B*U)
  const int p    = tid >> 1;          // chain index: b*DIM + col
  const int half = tid & 1;           // 0: unit=col, 1: unit=col+DIM
  const int b    = p >> 10;           // DIM == 1024
  const int col  = p & (DIM - 1);
  const int u    = col + (half << 10);

  // ---- per-thread constants (loaded/derived once) ----
  const float spw0  = softplus_init(w[2*u]);
  const float spw1  = softplus_init(w[2*u+1]);
  const float e0    = erev[2*u];
  const float e1    = erev[2*u+1];
  const float spw0e = spw0 * e0;
  const float spw1e = spw1 * e1;
  const float sg0   = sigma[2*u],  sg1 = sigma[2*u+1];
  const float mu0   = mu[2*u],     mu1 = mu[2*u+1];
  // sigmoid((v-mu)*sg) = 1/(1 + exp2(fma(v, -sg*L2E, mu*sg*L2E)))
  const float negA0 = -sg0 * L2E,  B0c = mu0 * sg0 * L2E;
  const float negA1 = -sg1 * L2E,  B1c = mu1 * sg1 * L2E;
  const float gl    = softplus_init(gleak[u]);
  const float glv   = gl * vleak[u];
  const float cmt   = softplus_init(cm[u]) * (float)ODE_UNFOLDS;
  const float dbase = cmt + gl + EPS;
  const float spsw  = softplus_init(sens_w[u]);
  const float ssg   = sens_sigma[u];
  const float smu   = sens_mu[u];
  const float negAs = -ssg * L2E,  Bsc = smu * ssg * L2E;
  const float serev = sens_erev[u];
  const float iw    = input_w[col];
  const float ib    = input_b[col];

  // partner's synapse-1 exp-arg constants: each lane computes the partner's t1
  // locally from its OWN v (same-cost fma), result swapped AFTER exp2 so the
  // DPP overlaps the own-path a0/p computation instead of heading the chain.
  const float negA1p = swap_adj(negA1);
  const float B1p    = swap_adj(B1c);

  const float* xp = inputs + ((size_t)b * T_STEPS) * DIM + col;

  // 4-deep x prefetch pipeline (hides HBM latency at 1 wave/SIMD)
  float xs0 = xp[0 * DIM];
  float xs1 = xp[1 * DIM];
  float xs2 = xp[2 * DIM];
  float xs3 = xp[3 * DIM];

  // state carried as rational pair: v == nume * r. init v=0 -> nume=0, r=1.
  // nn0/nn1/cn are the off-chain pre-multiplies of nume by the exp-arg slopes,
  // so the chain consumes r directly: z = fma(nn, r, B) (v never materialized).
  float nume = 0.0f;
  float r    = 1.0f;
  float nn0  = 0.0f;   // nume * negA0
  float nn1  = 0.0f;   // nume * negA1p
  float cn   = 0.0f;   // cmt  * nume

  for (int tb = 0; tb < T_STEPS; tb += 4) {
    const float c0 = xs0, c1 = xs1, c2 = xs2, c3 = xs3;
    if (tb + 4 < T_STEPS) {
      const float* nx = xp + (size_t)(tb + 4) * DIM;
      xs0 = nx[0 * DIM];
      xs1 = nx[1 * DIM];
      xs2 = nx[2 * DIM];
      xs3 = nx[3 * DIM];
    }
    #pragma unroll
    for (int j = 0; j < 4; ++j) {
      const float xr = (j == 0) ? c0 : (j == 1) ? c1 : (j == 2) ? c2 : c3;
      const float x  = fmaf(xr, iw, ib);
      // sensory synapse (once per step; off the unfold chain)
      const float ts    = fexp2(fmaf(x, negAs, Bsc));
      const float s     = spsw * frcp(1.0f + ts);
      const float ns    = fmaf(s, serev, glv);   // glv + num_s
      const float ds    = dbase + s;             // cmt + gl + eps + den_s
      const float dspw0 = ds + spw0;             // for the folded p-fma
      #pragma unroll
      for (int k = 0; k < ODE_UNFOLDS; ++k) {
        // scaled-through by a0*a1:
        //   nume = a1*(numerN*a0 + spw0e) + spw1e*a0
        //   deno = a1*(ds*a0 + spw0)     + spw1 *a0    ("+1" folded into dspw0)
        const float z0  = fmaf(nn0, r, B0c);      // = v*negA0 + B0c
        const float z1p = fmaf(nn1, r, B1p);      // partner's t1 arg, from MY v
        const float t0  = fexp2(z0);
        const float tp  = fexp2(z1p);
        const float t1  = swap_adj(tp);           // DPP off own path
        const float a0  = 1.0f + t0;
        const float numerN = fmaf(cn, r, ns);     // = cmt*v + ns (off-chain)
        const float q   = fmaf(numerN, a0, spw0e);
        const float e_t = spw1e * a0;
        const float pD  = fmaf(ds, t0, dspw0);    // chain: t0 -> pD (a0-add skipped)
        const float s_t = spw1 * a0;
        const float a1  = 1.0f + t1;
        nume            = fmaf(a1, q, e_t);
        const float deno = fmaf(a1, pD, s_t);
        // --- reciprocal WITHOUT the trans unit: scale-free bit seed + 3rd-order
        // refinement. r = r0*(1+e)(1+e^2)(1+e^4), rel err = e^8 <= ~4e-8.
        // 24 cy of fma links replaces v_rcp_f32's ~45 cy dependent latency.
        const float r0i = __int_as_float(0x7EF311C3 - __float_as_int(deno));
        const float er  = fmaf(-deno, r0i, 1.0f);
        const float p1  = 1.0f + er;
        const float e2  = er * er;
        const float p2  = fmaf(e2, p1, p1);
        const float e4  = e2 * e2;
        const float p3  = fmaf(e4, p2, p2);
        r = r0i * p3;
        // off-chain pre-multiplies for the next unfold (ready long before r)
        nn0 = nume * negA0;
        nn1 = nume * negA1p;
        cn  = cmt  * nume;
      }
    }
  }

  if (half == 0) {
    const float v = nume * r;
    out[(size_t)b * DIM + col] = fmaf(v, output_w[col], output_b[col]);
  }
}

extern "C" void kernel_launch(void* const* d_in, const int* in_sizes, int n_in,
                              void* d_out, int out_size, void* d_ws, size_t ws_size,
                              hipStream_t stream) {
  const float* inputs      = (const float*)d_in[0];
  const float* gleak       = (const float*)d_in[1];
  const float* vleak       = (const float*)d_in[2];
  const float* cm          = (const float*)d_in[3];
  const float* w           = (const float*)d_in[4];
  const float* sigma       = (const float*)d_in[5];
  const float* mu          = (const float*)d_in[6];
  const float* erev        = (const float*)d_in[7];
  const float* sens_w      = (const float*)d_in[8];
  const float* sens_sigma  = (const float*)d_in[9];
  const float* sens_mu     = (const float*)d_in[10];
  const float* sens_erev   = (const float*)d_in[11];
  const float* input_w     = (const float*)d_in[12];
  const float* input_b     = (const float*)d_in[13];
  const float* output_w    = (const float*)d_in[14];
  const float* output_b    = (const float*)d_in[15];

  const int B = in_sizes[0] / (T_STEPS * DIM);   // 32
  const int U = 2 * DIM;
  const int total_threads = B * U;               // 65536
  dim3 block(256);
  dim3 grid(total_threads / 256);                // 256 blocks -> 1 block/CU

  memcell_kernel<<<grid, block, 0, stream>>>(
      inputs, gleak, vleak, cm, w, sigma, mu, erev,
      sens_w, sens_sigma, sens_mu, sens_erev,
      input_w, input_b, output_w, output_b, (float*)d_out);
}

// Round 6
// 122.755 us; speedup vs baseline: 1.1951x; 1.0764x over previous
//
#include <hip/hip_runtime.h>

#define T_STEPS 128
#define DIM 1024
#define ODE_UNFOLDS 6
#define EPS 1e-8f
#define L2E 1.44269504088896340736f

__device__ __forceinline__ float fexp2(float x) { return __builtin_amdgcn_exp2f(x); }
__device__ __forceinline__ float frcp(float x)  { return __builtin_amdgcn_rcpf(x); }

__device__ __forceinline__ float softplus_init(float x) {
  // init-only (once per thread); x in (0,1] here so no overflow concerns
  return log2f(1.0f + exp2f(x * L2E)) * (1.0f / L2E);
}

// swap adjacent lane pairs (0<->1, 2<->3, ...): v_mov_b32_dpp quad_perm:[1,0,3,2]
// full-rate VALU; kept OFF the recurrence critical path (swap after exp2).
__device__ __forceinline__ float swap_adj(float x) {
  int y = __builtin_amdgcn_mov_dpp(__float_as_int(x), 0xB1, 0xF, 0xF, true);
  return __int_as_float(y);
}

// Chain-latency-bound serial recurrence: wall = 768 * dependent-chain latency.
// Chain: z-fma -> exp2 -> pD-fma -> deno-fma -> rcp  (3 VALU links + 2 trans).
// State carried as rational pair (nume, r); v is never materialized on-chain.
__global__ __launch_bounds__(256) void memcell_kernel(
    const float* __restrict__ inputs,      // (B,T,DIM)
    const float* __restrict__ gleak,       // (U)
    const float* __restrict__ vleak,       // (U)
    const float* __restrict__ cm,          // (U)
    const float* __restrict__ w,           // (U,2)
    const float* __restrict__ sigma,       // (U,2)
    const float* __restrict__ mu,          // (U,2)
    const float* __restrict__ erev,        // (U,2)
    const float* __restrict__ sens_w,      // (U)
    const float* __restrict__ sens_sigma,  // (U)
    const float* __restrict__ sens_mu,     // (U)
    const float* __restrict__ sens_erev,   // (U)
    const float* __restrict__ input_w,     // (DIM)
    const float* __restrict__ input_b,     // (DIM)
    const float* __restrict__ output_w,    // (DIM)
    const float* __restrict__ output_b,    // (DIM)
    float* __restrict__ out)               // (B,DIM)
{
  const int tid  = blockIdx.x * blockDim.x + threadIdx.x;  // [0, B*U)
  const int p    = tid >> 1;          // chain index: b*DIM + col
  const int half = tid & 1;           // 0: unit=col, 1: unit=col+DIM
  const int b    = p >> 10;           // DIM == 1024
  const int col  = p & (DIM - 1);
  const int u    = col + (half << 10);

  // ---- per-thread constants (loaded/derived once) ----
  const float spw0  = softplus_init(w[2*u]);
  const float spw1  = softplus_init(w[2*u+1]);
  const float e0    = erev[2*u];
  const float e1    = erev[2*u+1];
  const float spw0e = spw0 * e0;
  const float spw1e = spw1 * e1;
  const float sg0   = sigma[2*u],  sg1 = sigma[2*u+1];
  const float mu0   = mu[2*u],     mu1 = mu[2*u+1];
  // sigmoid((v-mu)*sg) = 1/(1 + exp2(fma(v, -sg*L2E, mu*sg*L2E)))
  const float negA0 = -sg0 * L2E,  B0c = mu0 * sg0 * L2E;
  const float negA1 = -sg1 * L2E,  B1c = mu1 * sg1 * L2E;
  const float gl    = softplus_init(gleak[u]);
  const float glv   = gl * vleak[u];
  const float cmt   = softplus_init(cm[u]) * (float)ODE_UNFOLDS;
  const float dbase = cmt + gl + EPS;
  const float spsw  = softplus_init(sens_w[u]);
  const float ssg   = sens_sigma[u];
  const float smu   = sens_mu[u];
  const float negAs = -ssg * L2E,  Bsc = smu * ssg * L2E;
  const float serev = sens_erev[u];
  const float iw    = input_w[col];
  const float ib    = input_b[col];

  // partner's synapse-1 exp-arg constants: each lane computes the partner's t1
  // locally from its OWN v (same-cost fma), result swapped AFTER exp2 so the
  // DPP overlaps the own-path a0/pD computation instead of heading the chain.
  const float negA1p = swap_adj(negA1);
  const float B1p    = swap_adj(B1c);

  const float* xp = inputs + ((size_t)b * T_STEPS) * DIM + col;

  // 4-deep x prefetch pipeline (hides HBM latency at 1 wave/SIMD)
  float xs0 = xp[0 * DIM];
  float xs1 = xp[1 * DIM];
  float xs2 = xp[2 * DIM];
  float xs3 = xp[3 * DIM];

  // rational-pair state: v == nume * r. init v=0 -> nume=0, r=1.
  // nn0/nn1/cn are off-chain pre-multiplies of nume (ready ~40cy before r),
  // so the chain consumes r directly: z = fma(nn, r, B).
  float nume = 0.0f;
  float r    = 1.0f;
  float nn0  = 0.0f;   // nume * negA0
  float nn1  = 0.0f;   // nume * negA1p
  float cn   = 0.0f;   // cmt  * nume

  for (int tb = 0; tb < T_STEPS; tb += 4) {
    const float c0 = xs0, c1 = xs1, c2 = xs2, c3 = xs3;
    if (tb + 4 < T_STEPS) {
      const float* nx = xp + (size_t)(tb + 4) * DIM;
      xs0 = nx[0 * DIM];
      xs1 = nx[1 * DIM];
      xs2 = nx[2 * DIM];
      xs3 = nx[3 * DIM];
    }
    #pragma unroll
    for (int j = 0; j < 4; ++j) {
      const float xr = (j == 0) ? c0 : (j == 1) ? c1 : (j == 2) ? c2 : c3;
      const float x  = fmaf(xr, iw, ib);
      // sensory synapse (once per step; off the unfold chain)
      const float ts    = fexp2(fmaf(x, negAs, Bsc));
      const float s     = spsw * frcp(1.0f + ts);
      const float ns    = fmaf(s, serev, glv);   // glv + num_s
      const float ds    = dbase + s;             // cmt + gl + eps + den_s
      const float dspw0 = ds + spw0;             // for the folded pD-fma
      #pragma unroll
      for (int k = 0; k < ODE_UNFOLDS; ++k) {
        // scaled-through by a0*a1 -> one rcp per unfold:
        //   nume = a1*(numerN*a0 + spw0e) + spw1e*a0
        //   deno = a1*(ds*a0 + spw0)     + spw1 *a0   ("+1" folded into dspw0)
        const float z0  = fmaf(nn0, r, B0c);      // = v*negA0 + B0c
        const float z1p = fmaf(nn1, r, B1p);      // partner's t1 arg, from MY v
        const float t0  = fexp2(z0);
        const float tp  = fexp2(z1p);
        const float numerN = fmaf(cn, r, ns);     // = cmt*v + ns (slack path)
        const float t1  = swap_adj(tp);           // DPP off own path
        const float a0  = 1.0f + t0;
        const float q   = fmaf(numerN, a0, spw0e);
        const float e_t = spw1e * a0;
        const float pD  = fmaf(ds, t0, dspw0);    // chain: t0 -> pD
        const float s_t = spw1 * a0;
        const float a1  = 1.0f + t1;
        nume             = fmaf(a1, q, e_t);
        const float deno = fmaf(a1, pD, s_t);     // chain: pD -> deno
        r                = frcp(deno);            // chain: deno -> r
        // off-chain pre-multiplies for the next unfold (fill stall slots)
        nn0 = nume * negA0;
        nn1 = nume * negA1p;
        cn  = cmt  * nume;
      }
    }
  }

  if (half == 0) {
    const float v = nume * r;
    out[(size_t)b * DIM + col] = fmaf(v, output_w[col], output_b[col]);
  }
}

extern "C" void kernel_launch(void* const* d_in, const int* in_sizes, int n_in,
                              void* d_out, int out_size, void* d_ws, size_t ws_size,
                              hipStream_t stream) {
  const float* inputs      = (const float*)d_in[0];
  const float* gleak       = (const float*)d_in[1];
  const float* vleak       = (const float*)d_in[2];
  const float* cm          = (const float*)d_in[3];
  const float* w           = (const float*)d_in[4];
  const float* sigma       = (const float*)d_in[5];
  const float* mu          = (const float*)d_in[6];
  const float* erev        = (const float*)d_in[7];
  const float* sens_w      = (const float*)d_in[8];
  const float* sens_sigma  = (const float*)d_in[9];
  const float* sens_mu     = (const float*)d_in[10];
  const float* sens_erev   = (const float*)d_in[11];
  const float* input_w     = (const float*)d_in[12];
  const float* input_b     = (const float*)d_in[13];
  const float* output_w    = (const float*)d_in[14];
  const float* output_b    = (const float*)d_in[15];

  const int B = in_sizes[0] / (T_STEPS * DIM);   // 32
  const int U = 2 * DIM;
  const int total_threads = B * U;               // 65536
  dim3 block(256);
  dim3 grid(total_threads / 256);                // 256 blocks -> 1 block/CU

  memcell_kernel<<<grid, block, 0, stream>>>(
      inputs, gleak, vleak, cm, w, sigma, mu, erev,
      sens_w, sens_sigma, sens_mu, sens_erev,
      input_w, input_b, output_w, output_b, (float*)d_out);
}